// Round 15
// baseline (397.747 us; speedup 1.0000x reference)
//
#include <hip/hip_runtime.h>
#include <math.h>

#define CDIV(a,b) (((a)+(b)-1)/(b))

typedef short short8 __attribute__((ext_vector_type(8)));
typedef float f32x4  __attribute__((ext_vector_type(4)));
typedef unsigned short u16;

__device__ __forceinline__ float warp_sum(float v){
  #pragma unroll
  for (int o=32;o;o>>=1) v += __shfl_down(v,o);
  return v;
}
__device__ __forceinline__ int warp_min(int v){
  #pragma unroll
  for (int o=32;o;o>>=1) v = min(v,__shfl_down(v,o));
  return v;
}
__device__ __forceinline__ u16 f2bf(float f){
  unsigned u = __float_as_uint(f);
  unsigned r = 0x7fffu + ((u>>16)&1u);
  return (u16)((u + r)>>16);
}
__device__ __forceinline__ float bl(u16 v){ return __uint_as_float(((unsigned)v)<<16); }

// ---------- fused row-dot (qe for entities, qr for relations) ----------
__global__ __launch_bounds__(256)
void k_rowdot_all(const float* __restrict__ ent, const float* __restrict__ nontext,
                  const float* __restrict__ q, float* __restrict__ qe,
                  int N, int Ntext,
                  const float* __restrict__ rel, float* __restrict__ qr, int R, int nb1){
  int wid = threadIdx.x>>6, lane = threadIdx.x&63;
  const float* src; float* dst; int row;
  if ((int)blockIdx.x < nb1){
    row = blockIdx.x*4 + wid; if (row >= N) return;
    src = (row < Ntext) ? (ent + (size_t)row*256) : nontext;
    dst = qe;
  } else {
    row = (blockIdx.x-nb1)*4 + wid; if (row >= R) return;
    src = rel + (size_t)row*256;
    dst = qr;
  }
  float4 a = *(const float4*)(src + lane*4);
  float4 b = *(const float4*)(q + lane*4);
  float s = a.x*b.x + a.y*b.y + a.z*b.z + a.w*b.w;
  s = warp_sum(s);
  if (!lane) dst[row] = s;
}

// ---------- tri + per-block max + degree hist (fused) ----------
__global__ __launch_bounds__(256)
void k_tri(const int* __restrict__ h, const int* __restrict__ r,
           const int* __restrict__ t, const float* __restrict__ qe,
           const float* __restrict__ qr, float* __restrict__ tri,
           float* __restrict__ bmax, int* __restrict__ degh, int* __restrict__ degi, int E){
  __shared__ float red[256];
  int e = blockIdx.x*256 + threadIdx.x;
  float v = -INFINITY;
  if (e < E){
    int hh=h[e], rr=r[e], tt=t[e];
    v = qe[hh] + qr[rr] + qe[tt];
    tri[e] = v;
    atomicAdd(&degh[hh], 1);
    atomicAdd(&degi[tt], 1);
  }
  red[threadIdx.x]=v; __syncthreads();
  for (int s=128;s;s>>=1){ if ((int)threadIdx.x<s) red[threadIdx.x]=fmaxf(red[threadIdx.x],red[threadIdx.x+s]); __syncthreads(); }
  if (!threadIdx.x) bmax[blockIdx.x]=red[0];
}

// ---------- 32nd-largest of block maxes: single wave, no barriers ----------
__global__ __launch_bounds__(64)
void k_thresh(const float* __restrict__ bmax, float* __restrict__ thrT, int nb){
  int lane = threadIdx.x;
  float m = -INFINITY;
  for (int i=lane; i<nb; i+=64) m = fmaxf(m, bmax[i]);
  for (int it=0; it<32; it++){
    float bv = m; int bln = lane;
    #pragma unroll
    for (int o=32;o;o>>=1){
      float ov = __shfl_down(bv,o);
      int   ol = __shfl_down(bln,o);
      if (ov>bv){ bv=ov; bln=ol; }
    }
    float mv = __shfl(bv,0);
    int   wl = __shfl(bln,0);
    if (lane==wl) m = -INFINITY;
    if (it==31 && lane==0) thrT[0]=mv;
  }
}

__global__ void k_compact(const float* __restrict__ tri, const float* __restrict__ thrT,
                          int* __restrict__ cnt, int* __restrict__ ci, float* __restrict__ cv, int E){
  int e = blockIdx.x*256 + threadIdx.x; if (e>=E) return;
  float v = tri[e];
  if (v >= thrT[0]){
    int p = atomicAdd(cnt, 1);
    ci[p]=e; cv[p]=v;
  }
}

// ---------- final top-32 + masks: single wave, NO per-lane arrays ----------
__global__ __launch_bounds__(64)
void k_final32(const int* __restrict__ ci, const float* __restrict__ cv, const int* __restrict__ cnt,
               int* __restrict__ ai, float* __restrict__ as,
               const int* __restrict__ h_ids, const int* __restrict__ t_ids,
               const int* __restrict__ topicId, int nTopic,
               float* __restrict__ topic, float* __restrict__ amask){
  int lane = threadIdx.x;
  int C = *cnt; if (C > 1024) C = 1024;
  int nIter = CDIV(C,64);
  unsigned selMask = 0;
  int myai=0; float myas=0.f;
  for (int it=0; it<32; it++){
    float bv=-INFINITY; int bi=0x7fffffff; int bj=-1;
    for (int j=0;j<nIter;j++){
      int p = lane + j*64;
      if (p < C && !((selMask>>j)&1u)){
        float v = cv[p]; int idx = ci[p];
        if (v>bv || (v==bv && idx<bi)){ bv=v; bi=idx; bj=j; }
      }
    }
    int bln = lane;
    #pragma unroll
    for (int o=32;o;o>>=1){
      float ov=__shfl_down(bv,o); int oi=__shfl_down(bi,o);
      int   oj=__shfl_down(bj,o); int ol=__shfl_down(bln,o);
      if (ov>bv || (ov==bv && oi<bi)){ bv=ov; bi=oi; bj=oj; bln=ol; }
    }
    float wv=__shfl(bv,0); int wi=__shfl(bi,0);
    int   wj=__shfl(bj,0); int wl=__shfl(bln,0);
    if (lane==wl) selMask |= (1u<<wj);
    if (lane==it){ myai=wi; myas=wv; }
  }
  if (lane<32){
    ai[lane]=myai; as[lane]=myas;
    int e = myai;
    amask[h_ids[e]]=1.f;
    amask[t_ids[e]]=1.f;
  }
  if (lane<nTopic) topic[topicId[lane]]=1.f;
}

// ---------- CSR build (both directions, fused scans) ----------
__global__ void k_scan1(const int* __restrict__ degT, const int* __restrict__ degH,
                        int* __restrict__ offsT, int* __restrict__ offsH,
                        int* __restrict__ bsum, int N, int nb){
  __shared__ int s[256];
  int which = (int)blockIdx.x >= nb;
  int b = which ? blockIdx.x - nb : blockIdx.x;
  const int* deg = which ? degH : degT;
  int* offs = which ? offsH : offsT;
  int i = b*256 + threadIdx.x;
  int v = (i<N) ? deg[i] : 0;
  s[threadIdx.x] = v; __syncthreads();
  #pragma unroll
  for (int o=1;o<256;o<<=1){
    int add = (threadIdx.x>=(unsigned)o) ? s[threadIdx.x-o] : 0; __syncthreads();
    s[threadIdx.x] += add; __syncthreads();
  }
  if (i<N) offs[i] = s[threadIdx.x] - v;
  if (threadIdx.x==255) bsum[blockIdx.x] = s[255];
}
__global__ void k_scan2two(int* __restrict__ bsum, int nb){
  __shared__ int s[256];
  int t=threadIdx.x;
  int half = t>>7, idx = t&127;
  int v = (idx<nb)? bsum[half*nb+idx] : 0;
  s[t]=v; __syncthreads();
  #pragma unroll
  for (int o=1;o<128;o<<=1){ int add=(idx>=o)?s[t-o]:0; __syncthreads(); s[t]+=add; __syncthreads(); }
  if (idx<nb) bsum[half*nb+idx] = s[t]-v;
}
__global__ void k_scan3(int* __restrict__ offsT, int* __restrict__ offsH,
                        const int* __restrict__ bsum,
                        int* __restrict__ curT, int* __restrict__ curH, int N, int nb){
  int which = (int)blockIdx.x >= nb;
  int b = which ? blockIdx.x - nb : blockIdx.x;
  int i = b*256+threadIdx.x; if (i>=N) return;
  int* offs = which ? offsH : offsT;
  int* cur  = which ? curH  : curT;
  int o = offs[i] + bsum[blockIdx.x];
  offs[i]=o; cur[i]=o;
}
__global__ void k_place(const int* __restrict__ h, const int* __restrict__ r,
                        const int* __restrict__ t,
                        int* __restrict__ curT, int* __restrict__ curH,
                        int2* __restrict__ ehr, int* __restrict__ eIdx,
                        int* __restrict__ etH, int E){
  int e = blockIdx.x*256+threadIdx.x; if (e>=E) return;
  int hh=h[e], tt=t[e];
  int pos = atomicAdd(&curT[tt], 1);
  ehr[pos] = make_int2(hh, r[e]);
  eIdx[pos] = e;
  int posh = atomicAdd(&curH[hh], 1);
  etH[posh] = tt;
}

// ---------- DDE pair (grid.y: 0 = T-direction, 1 = H-direction) ----------
__global__ __launch_bounds__(256)
void k_dde2(const int* __restrict__ offsT, const int* __restrict__ degT, const int2* __restrict__ ehr,
            const int* __restrict__ offsH, const int* __restrict__ degH, const int* __restrict__ etH,
            const float* __restrict__ s0, const float* __restrict__ s1,
            float* __restrict__ sn0, float* __restrict__ sn1,
            float* __restrict__ pe4, int c0, int c1,
            const float* __restrict__ amask, int* __restrict__ dist0, int N){
  int wid=threadIdx.x>>6, lane=threadIdx.x&63;
  int i = blockIdx.x*4+wid; if (i>=N) return;
  int dir = blockIdx.y;
  const int* offs = dir ? offsH : offsT;
  const int* deg  = dir ? degH  : degT;
  const float* s  = dir ? s1 : s0;
  float* sn       = dir ? sn1 : sn0;
  int col         = dir ? c1 : c0;
  int start=offs[i], cnt=deg[i];
  float a=0.f;
  if (dir){
    for (int k=lane;k<cnt;k+=64) a += s[etH[start+k]];
  } else {
    for (int k=lane;k<cnt;k+=64) a += s[ehr[start+k].x];
  }
  a = warp_sum(a);
  if (!lane){
    float v = a / fmaxf((float)cnt,1.f);
    if (sn) sn[i]=v;
    pe4[i*4+col]=v;
    if (dist0 && !dir) dist0[i] = (amask[i]>0.f)?0:4;
  }
}

// ---------- BFS via CSR gather ----------
__global__ __launch_bounds__(256)
void k_bfs_g(const int* __restrict__ offsT, const int* __restrict__ degT, const int2* __restrict__ ehr,
             const int* __restrict__ offsH, const int* __restrict__ degH, const int* __restrict__ etH,
             const int* __restrict__ din, int* __restrict__ dout, int N){
  int wid=threadIdx.x>>6, lane=threadIdx.x&63;
  int i = blockIdx.x*4+wid; if (i>=N) return;
  int sT=offsT[i], cT=degT[i];
  int sH=offsH[i], cH=degH[i];
  int best = 4;
  for (int k=lane;k<cT;k+=64) best = min(best, din[ehr[sT+k].x]+1);
  for (int k=lane;k<cH;k+=64) best = min(best, din[etH[sH+k]]+1);
  best = warp_min(best);
  if (!lane) dout[i] = min(din[i], best);
}

// ---------- fused weight pack + small dense tail (distW, encnt, bias2) ----------
__global__ __launch_bounds__(64)
void k_packall(const float* __restrict__ W_enc, const float* __restrict__ W_msg,
               const float* __restrict__ W_gate, const float* __restrict__ W_upd,
               const float* __restrict__ W1, u16* __restrict__ pbAll,
               const float* __restrict__ dist_e, float* __restrict__ distW,
               const float* __restrict__ nontext, float* __restrict__ encnt,
               const float* __restrict__ q, const float* __restrict__ b1,
               float* __restrict__ bias2){
  int f = blockIdx.x, lane = threadIdx.x;
  if (f >= 2048){
    int b = f - 2048;
    if (b < 5){
      const float* Wpe = W_enc + (256+4)*256;
      #pragma unroll
      for (int jj=0;jj<4;jj++){
        int j = lane + jj*64;
        float s=0.f;
        #pragma unroll
        for (int p=0;p<16;p++) s += dist_e[b*16+p]*Wpe[p*256+j];
        distW[b*256+j]=s;
      }
    } else if (b == 5){
      #pragma unroll
      for (int jj=0;jj<4;jj++){
        int j = lane + jj*64;
        float s=0.f;
        for (int k=0;k<256;k++) s += nontext[k]*W_enc[k*256+j];
        encnt[j]=s;
      }
    } else {
      #pragma unroll
      for (int jj=0;jj<4;jj++){
        int j = lane + jj*64;
        float s=b1[j];
        for (int k=0;k<256;k++) s += q[k]*W1[k*256+j];
        bias2[j]=s;
      }
    }
    return;
  }
  int tgt, fid, nt16;
  if      (f < 128) { tgt=0; fid=f;      nt16=16; }
  else if (f < 256) { tgt=1; fid=f-128;  nt16=16; }
  else if (f < 384) { tgt=2; fid=f-256;  nt16=16; }
  else if (f < 896) { tgt=3; fid=f-384;  nt16=32; }
  else if (f < 1408){ tgt=4; fid=f-896;  nt16=32; }
  else if (f < 1792){ tgt=5; fid=f-1408; nt16=48; }
  else              { tgt=6; fid=f-1792; nt16=32; }
  int ks = fid/nt16, nt = fid%nt16;
  int kb = ks*32 + 8*(lane>>4);
  int n  = nt*16 + (lane&15);
  u16 v[8];
  #pragma unroll
  for (int i=0;i<8;i++){
    int k = kb+i;
    float x;
    if (tgt==0) x = W_enc[(size_t)k*256+n];
    else if (tgt==1) x = W_msg[(size_t)k*256+n];
    else if (tgt==2) x = W_msg[(size_t)(512+k)*256+n];
    else if (tgt==3 || tgt==4){
      const float* Wg = W_gate + (tgt==4 ? (size_t)512*256 : 0);
      const float* Wu = W_upd  + (tgt==4 ? (size_t)256*256 : 0);
      int blk = n>>4, c = ((blk>>1)<<4) | (n&15);
      if ((blk&1)==0) x = Wg[(size_t)k*256+c];
      else            x = (k<256) ? 0.f : Wu[(size_t)(k-256)*256+c];
    }
    else if (tgt==5){
      if (n<256)      x = W_msg[(size_t)(256+k)*256+n];
      else if (n<512) x = W_msg[(size_t)(768+k)*256+(n-256)];
      else            x = W1[(size_t)(512+k)*256+(n-512)];
    } else {
      if (n<256) x = W1[(size_t)(256+k)*256+n];
      else       x = W1[(size_t)(768+k)*256+(n-256)];
    }
    v[i]=f2bf(x);
  }
  *(uint4*)(pbAll + ((size_t)f*64+lane)*8) = *(uint4*)v;
}

// pack fp32 [256][512] -> 256 frags
__global__ __launch_bounds__(64)
void k_packf32(const float* __restrict__ W, u16* __restrict__ Bp){
  int f = blockIdx.x, lane = threadIdx.x;
  int ks = f/32, nt = f%32;
  int kb = ks*32 + 8*(lane>>4);
  int n  = nt*16 + (lane&15);
  u16 v[8];
  #pragma unroll
  for (int i=0;i<8;i++) v[i] = f2bf(W[(size_t)(kb+i)*512 + n]);
  *(uint4*)(Bp + ((size_t)f*64+lane)*8) = *(uint4*)v;
}

// ---------- MFMA bf16 GEMM (column-split via grid.y = CT; MR row-frags/wave) ----------
template<int NCOLS, int CT, int MODE, bool AF32, int MR>
__global__ __launch_bounds__(256)
void k_bgemm(const float* __restrict__ A1f, const u16* __restrict__ A2a,
             const u16* __restrict__ A2b, int K1,
             const u16* __restrict__ Bp, void* __restrict__ Cout,
             const float* __restrict__ xb, const float* __restrict__ W_enc,
             const float* __restrict__ pe4, const int* __restrict__ dist,
             const float* __restrict__ topic, const float* __restrict__ amask,
             const float* __restrict__ distW,
             int M, int K)
{
  constexpr int NT16 = NCOLS/16;
  constexpr int CPB  = NCOLS/CT;
  constexpr int NREP = CPB/32;
  const int tid  = threadIdx.x;
  const int lane = tid & 63;
  const int w    = tid >> 6;
  const int wr   = w >> 1, wc = w & 1;
  const int ct   = blockIdx.y;
  const int row0 = (blockIdx.x*2 + wr)*(16*MR);
  const int lrow = lane & 15;
  const int kc   = lane >> 4;
  int arow[MR];
  #pragma unroll
  for (int m=0;m<MR;m++){
    int rr = row0 + m*16 + lrow;
    arow[m] = (rr >= M) ? M-1 : rr;
  }

  f32x4 acc[MR][NREP];
  #pragma unroll
  for (int m=0;m<MR;m++)
    #pragma unroll
    for (int n=0;n<NREP;n++) acc[m][n] = (f32x4){0.f,0.f,0.f,0.f};

  const int ksteps = K/32;
  const int fcolBase = ct*(CPB/16) + wc*NREP;

  auto do_step = [&](short8* af, int ks){
    const u16* bp = Bp + ((size_t)(ks*NT16 + fcolBase)*64 + lane)*8;
    #pragma unroll
    for (int n=0;n<NREP;n++){
      short8 bf = *(const short8*)(bp + (size_t)n*64*8);
      #pragma unroll
      for (int m=0;m<MR;m++)
        acc[m][n] = __builtin_amdgcn_mfma_f32_16x16x32_bf16(af[m], bf, acc[m][n], 0, 0, 0);
    }
  };

  if (AF32){
    for (int ks=0; ks<ksteps; ks++){
      short8 af[MR];
      #pragma unroll
      for (int m=0;m<MR;m++){
        const float* ap = A1f + (size_t)arow[m]*256 + ks*32 + kc*8;
        float4 a0 = *(const float4*)ap;
        float4 a1 = *(const float4*)(ap+4);
        af[m][0]=(short)f2bf(a0.x); af[m][1]=(short)f2bf(a0.y); af[m][2]=(short)f2bf(a0.z); af[m][3]=(short)f2bf(a0.w);
        af[m][4]=(short)f2bf(a1.x); af[m][5]=(short)f2bf(a1.y); af[m][6]=(short)f2bf(a1.z); af[m][7]=(short)f2bf(a1.w);
      }
      do_step(af, ks);
    }
  } else {
    int s1 = K1>>5; if (s1 > ksteps) s1 = ksteps;
    for (int ks=0; ks<s1; ks++){
      short8 af[MR];
      #pragma unroll
      for (int m=0;m<MR;m++)
        af[m] = *(const short8*)(A2a + (size_t)arow[m]*256 + ks*32 + kc*8);
      do_step(af, ks);
    }
    for (int ks=s1; ks<ksteps; ks++){
      short8 af[MR];
      #pragma unroll
      for (int m=0;m<MR;m++)
        af[m] = *(const short8*)(A2b + (size_t)arow[m]*256 + (ks-s1)*32 + kc*8);
      do_step(af, ks);
    }
  }

  #pragma unroll
  for (int m=0;m<MR;m++){
    #pragma unroll
    for (int r=0;r<4;r++){
      int orow = row0 + m*16 + 4*kc + r;
      if (orow >= M) continue;
      if (MODE==0 || MODE==1){
        #pragma unroll
        for (int n=0;n<NREP;n++){
          int col = ct*CPB + wc*(CPB/2) + n*16 + lrow;
          float v = acc[m][n][r];
          if (MODE==0) ((float*)Cout)[(size_t)orow*NCOLS + col] = v;
          else         ((u16*)Cout)[(size_t)orow*NCOLS + col] = f2bf(v);
        }
      } else if (MODE==5){
        float tp = topic[orow];
        #pragma unroll
        for (int n=0;n<NREP;n++){
          int col = ct*CPB + wc*(CPB/2) + n*16 + lrow;
          float v = acc[m][n][r] + tp*xb[col];
          ((u16*)Cout)[(size_t)orow*NCOLS + col] = f2bf(v);
        }
      } else if (MODE==6){
        #pragma unroll
        for (int n=0;n<NREP;n++){
          int col = ct*CPB + wc*(CPB/2) + n*16 + lrow;
          float v = acc[m][n][r];
          if (col >= 512) v += xb[col-512];
          ((u16*)Cout)[(size_t)orow*NCOLS + col] = f2bf(v);
        }
      } else if (MODE==3){
        float p0=pe4[orow*4+0], p1=pe4[orow*4+1], p2=pe4[orow*4+2], p3=pe4[orow*4+3];
        int dd=dist[orow];
        float tp=topic[orow], am=amask[orow];
        const float* Wpe = W_enc + 256*256;
        #pragma unroll
        for (int n=0;n<NREP;n++){
          int col = ct*CPB + wc*(CPB/2) + n*16 + lrow;
          float v = acc[m][n][r];
          v += xb[col] + Wpe[22*256+col]
             + p0*Wpe[col] + p1*Wpe[256+col] + p2*Wpe[512+col] + p3*Wpe[768+col]
             + distW[dd*256+col] + tp*Wpe[20*256+col] + am*Wpe[21*256+col];
          ((u16*)Cout)[(size_t)orow*256 + col] = f2bf(fmaxf(v, 0.f));
        }
      } else { // MODE 4
        #pragma unroll
        for (int k=0;k<NREP/2;k++){
          int col = (ct*(CPB/32) + wc*(CPB/64) + k)*16 + lrow;
          size_t idx = (size_t)orow*256 + col;
          float g = 1.f/(1.f+expf(-acc[m][2*k][r]));
          float u = tanhf(acc[m][2*k+1][r]);
          float v = bl(A2a[idx]) + g*u;
          ((u16*)Cout)[idx] = f2bf(v);
        }
      }
    }
  }
}

// ---------- non-text rows of encoder ----------
__global__ __launch_bounds__(256)
void k_encnt_fill(const float* __restrict__ encnt, const float* __restrict__ b_enc,
                  const float* __restrict__ W_enc, const float* __restrict__ pe4,
                  const int* __restrict__ dist, const float* __restrict__ topic,
                  const float* __restrict__ amask, const float* __restrict__ distW,
                  u16* __restrict__ hB, int Ntext){
  int i = Ntext + blockIdx.x, j = threadIdx.x;
  const float* Wpe = W_enc + 256*256;
  float p0=pe4[i*4+0], p1=pe4[i*4+1], p2=pe4[i*4+2], p3=pe4[i*4+3];
  int d = dist[i];
  float tp = topic[i], am = amask[i];
  float v = encnt[j] + b_enc[j] + Wpe[22*256+j]
          + p0*Wpe[j] + p1*Wpe[256+j] + p2*Wpe[512+j] + p3*Wpe[768+j]
          + distW[d*256+j] + tp*Wpe[20*256+j] + am*Wpe[21*256+j];
  hB[(size_t)i*256+j] = f2bf(fmaxf(v, 0.f));
}

// ---------- GNN aggregation: wave per node, 4 cols/lane, 4x unroll ----------
__global__ __launch_bounds__(256)
void k_agg(const int* __restrict__ offs, const int* __restrict__ degi,
           const int2* __restrict__ ehr,
           const u16* __restrict__ hm, const u16* __restrict__ relC, int colOff,
           u16* __restrict__ agg, int N){
  int wid = threadIdx.x>>6, lane = threadIdx.x&63;
  int i = blockIdx.x*4 + wid; if (i>=N) return;
  int start = offs[i], cnt = degi[i];
  int c4 = lane*4;
  float a0=0.f,a1=0.f,a2=0.f,a3=0.f;
  int k=0;
  for (; k+3<cnt; k+=4){
    int2 hr[4]; uint2 ua[4], ub[4];
    #pragma unroll
    for (int j=0;j<4;j++) hr[j] = ehr[start+k+j];
    #pragma unroll
    for (int j=0;j<4;j++){
      ua[j] = *(const uint2*)(hm + (size_t)hr[j].x*256 + c4);
      ub[j] = *(const uint2*)(relC + (size_t)hr[j].y*768 + colOff + c4);
    }
    #pragma unroll
    for (int j=0;j<4;j++){
      a0 += fmaxf(bl((u16)(ua[j].x&0xffff))+bl((u16)(ub[j].x&0xffff)),0.f);
      a1 += fmaxf(bl((u16)(ua[j].x>>16))  +bl((u16)(ub[j].x>>16)),  0.f);
      a2 += fmaxf(bl((u16)(ua[j].y&0xffff))+bl((u16)(ub[j].y&0xffff)),0.f);
      a3 += fmaxf(bl((u16)(ua[j].y>>16))  +bl((u16)(ub[j].y>>16)),  0.f);
    }
  }
  for (; k<cnt; k++){
    int2 hr = ehr[start+k];
    uint2 ua = *(const uint2*)(hm + (size_t)hr.x*256 + c4);
    uint2 ub = *(const uint2*)(relC + (size_t)hr.y*768 + colOff + c4);
    a0 += fmaxf(bl((u16)(ua.x&0xffff))+bl((u16)(ub.x&0xffff)),0.f);
    a1 += fmaxf(bl((u16)(ua.x>>16))  +bl((u16)(ub.x>>16)),  0.f);
    a2 += fmaxf(bl((u16)(ua.y&0xffff))+bl((u16)(ub.y&0xffff)),0.f);
    a3 += fmaxf(bl((u16)(ua.y>>16))  +bl((u16)(ub.y>>16)),  0.f);
  }
  uint2 o;
  o.x = (unsigned)f2bf(a0) | ((unsigned)f2bf(a1)<<16);
  o.y = (unsigned)f2bf(a2) | ((unsigned)f2bf(a3)<<16);
  *(uint2*)(agg + (size_t)i*256 + c4) = o;
}

// ---------- scorer: wave per node (t-sorted), topic+bias2 pre-folded, 4x unroll ----------
__global__ __launch_bounds__(256)
void k_score(const int* __restrict__ offs, const int* __restrict__ degi,
             const int2* __restrict__ ehr, const int* __restrict__ eIdx,
             const u16* __restrict__ UHT, const u16* __restrict__ relC,
             const float* __restrict__ W2,
             const float* __restrict__ b2, float* __restrict__ out, int N){
  int wid = threadIdx.x>>6, lane = threadIdx.x&63;
  int i = blockIdx.x*4 + wid; if (i>=N) return;
  int start = offs[i], cnt = degi[i];
  if (!cnt) return;
  int c = lane*4;
  uint2 ud = *(const uint2*)(UHT + (size_t)i*512 + 256 + c);
  float b0 = bl((u16)(ud.x&0xffff)), b1v = bl((u16)(ud.x>>16));
  float b2v= bl((u16)(ud.y&0xffff)), b3  = bl((u16)(ud.y>>16));
  float4 w = *(const float4*)(W2 + c);
  float bout = b2[0];
  int k=0;
  for (; k+3<cnt; k+=4){
    int2 e[4]; uint2 ua[4], ub[4];
    #pragma unroll
    for (int j=0;j<4;j++) e[j] = ehr[start+k+j];
    #pragma unroll
    for (int j=0;j<4;j++){
      ua[j] = *(const uint2*)(UHT + (size_t)e[j].x*512 + c);
      ub[j] = *(const uint2*)(relC + (size_t)e[j].y*768 + 512 + c);
    }
    float p[4];
    #pragma unroll
    for (int j=0;j<4;j++){
      p[j] = fmaxf(b0 + bl((u16)(ua[j].x&0xffff)) + bl((u16)(ub[j].x&0xffff)),0.f)*w.x
           + fmaxf(b1v+ bl((u16)(ua[j].x>>16))    + bl((u16)(ub[j].x>>16)),  0.f)*w.y
           + fmaxf(b2v+ bl((u16)(ua[j].y&0xffff)) + bl((u16)(ub[j].y&0xffff)),0.f)*w.z
           + fmaxf(b3 + bl((u16)(ua[j].y>>16))    + bl((u16)(ub[j].y>>16)),  0.f)*w.w;
    }
    #pragma unroll
    for (int j=0;j<4;j++) p[j] = warp_sum(p[j]);
    if (!lane){
      #pragma unroll
      for (int j=0;j<4;j++) out[eIdx[start+k+j]] = p[j] + bout;
    }
  }
  for (; k<cnt; k++){
    int2 e0 = ehr[start+k];
    uint2 ua = *(const uint2*)(UHT + (size_t)e0.x*512 + c);
    uint2 ub = *(const uint2*)(relC + (size_t)e0.y*768 + 512 + c);
    float p = fmaxf(b0 + bl((u16)(ua.x&0xffff)) + bl((u16)(ub.x&0xffff)),0.f)*w.x
            + fmaxf(b1v+ bl((u16)(ua.x>>16))    + bl((u16)(ub.x>>16)),  0.f)*w.y
            + fmaxf(b2v+ bl((u16)(ua.y&0xffff)) + bl((u16)(ub.y&0xffff)),0.f)*w.z
            + fmaxf(b3 + bl((u16)(ua.y>>16))    + bl((u16)(ub.y>>16)),  0.f)*w.w;
    p = warp_sum(p);
    if (!lane) out[eIdx[start+k]] = p + bout;
  }
}

// ---------- anchor patch (32 edges; topic+bias2 already folded in tables) ----------
__global__ __launch_bounds__(256)
void k_patch(const int* __restrict__ ai, const float* __restrict__ as,
             const int* __restrict__ h_ids, const int* __restrict__ r_ids, const int* __restrict__ t_ids,
             const u16* __restrict__ UHT, const u16* __restrict__ relC,
             const float* __restrict__ W1s, const float* __restrict__ W2,
             const float* __restrict__ b2, float* __restrict__ out){
  int wid = threadIdx.x>>6, lane = threadIdx.x&63;
  int k = blockIdx.x*4 + wid; if (k>=32) return;
  int e = ai[k];
  int h=h_ids[e], r=r_ids[e], t=t_ids[e];
  float aS = as[k];
  int c = lane*4;
  uint2 ua = *(const uint2*)(UHT + (size_t)h*512 + c);
  uint2 ud = *(const uint2*)(UHT + (size_t)t*512 + 256 + c);
  uint2 ub = *(const uint2*)(relC + (size_t)r*768 + 512 + c);
  float4 w0 = *(const float4*)(W1s + 0*256 + c);
  float4 w1 = *(const float4*)(W1s + 1*256 + c);
  float4 acc;
  acc.x = bl((u16)(ua.x&0xffff))+bl((u16)(ub.x&0xffff))+bl((u16)(ud.x&0xffff)) + w0.x + aS*w1.x;
  acc.y = bl((u16)(ua.x>>16))  +bl((u16)(ub.x>>16))  +bl((u16)(ud.x>>16))   + w0.y + aS*w1.y;
  acc.z = bl((u16)(ua.y&0xffff))+bl((u16)(ub.y&0xffff))+bl((u16)(ud.y&0xffff)) + w0.z + aS*w1.z;
  acc.w = bl((u16)(ua.y>>16))  +bl((u16)(ub.y>>16))  +bl((u16)(ud.y>>16))   + w0.w + aS*w1.w;
  acc.x=fmaxf(acc.x,0.f); acc.y=fmaxf(acc.y,0.f); acc.z=fmaxf(acc.z,0.f); acc.w=fmaxf(acc.w,0.f);
  float4 w = *(const float4*)(W2 + c);
  float p = acc.x*w.x + acc.y*w.y + acc.z*w.z + acc.w*w.w;
  p = warp_sum(p);
  if (!lane) out[e] = p + b2[0];
}

// ---------- host ----------
extern "C" void kernel_launch(void* const* d_in, const int* in_sizes, int n_in,
                              void* d_out, int out_size, void* d_ws, size_t ws_size,
                              hipStream_t stream)
{
  const int*   h_ids   = (const int*)d_in[0];
  const int*   r_ids   = (const int*)d_in[1];
  const int*   t_ids   = (const int*)d_in[2];
  const float* q       = (const float*)d_in[3];
  const float* ent     = (const float*)d_in[4];
  const float* rel     = (const float*)d_in[5];
  const int*   topicId = (const int*)d_in[6];
  const float* nontext = (const float*)d_in[9];
  const float* dist_e  = (const float*)d_in[10];
  const float* W_enc   = (const float*)d_in[11];
  const float* b_enc   = (const float*)d_in[12];
  const float* W_msg   = (const float*)d_in[13];
  const float* W_gate  = (const float*)d_in[14];
  const float* W_upd   = (const float*)d_in[15];
  const float* W_out   = (const float*)d_in[16];
  const float* W1      = (const float*)d_in[17];
  const float* b1      = (const float*)d_in[18];
  const float* W2      = (const float*)d_in[19];
  const float* b2      = (const float*)d_in[20];
  float* out = (float*)d_out;

  const int E = in_sizes[0];
  const int Ntext = in_sizes[4]/256;
  const int R = in_sizes[5]/256;
  const int NT = 500;
  const int N = Ntext + NT;
  const int nTopic = in_sizes[6];
  const int BIGK1 = 1<<28;

  char* ws = (char*)d_ws;
  size_t off = 0;
  auto alloc = [&](size_t bytes)->void*{
    size_t o = (off + 255) & ~(size_t)255;
    off = o + bytes;
    return (void*)(ws + o);
  };
  // big activations (all-bf16 h)
  u16*   hB1   = (u16*)  alloc((size_t)N*256*2);
  u16*   hB2   = (u16*)  alloc((size_t)N*256*2);
  u16*   hmB   = (u16*)  alloc((size_t)N*256*2);
  u16*   aggB  = (u16*)  alloc((size_t)N*256*2);
  u16*   relC  = (u16*)  alloc((size_t)R*768*2);
  u16*   UHT   = (u16*)  alloc((size_t)N*512*2);
  float* WcombF= (float*)alloc((size_t)256*512*4);
  u16*   pbWcomb=(u16*)  alloc((size_t)256*512*2);
  // small
  float* qe    = (float*)alloc((size_t)N*4);
  float* qr    = (float*)alloc((size_t)R*4);
  float* tri   = (float*)alloc((size_t)E*4);
  float* bmax  = (float*)alloc(1024*4);
  float* thrT  = (float*)alloc(4);
  int*   ci    = (int*)  alloc((size_t)E*4);
  float* cv    = (float*)alloc((size_t)E*4);
  int*   ai    = (int*)  alloc(32*4);
  float* as    = (float*)alloc(32*4);
  float* pe4   = (float*)alloc((size_t)N*16);
  int*   dA    = (int*)  alloc((size_t)N*4);
  int*   dB    = (int*)  alloc((size_t)N*4);
  float* distW = (float*)alloc(5*256*4);
  float* encnt = (float*)alloc(256*4);
  float* bias2 = (float*)alloc(256*4);
  int*   offsT = (int*)  alloc((size_t)N*4);
  int*   offsH = (int*)  alloc((size_t)N*4);
  int*   bsum  = (int*)  alloc(256*4);
  int*   curT  = (int*)  alloc((size_t)N*4);
  int*   curH  = (int*)  alloc((size_t)N*4);
  int2*  ehr   = (int2*) alloc((size_t)E*8);
  int*   eIdx  = (int*)  alloc((size_t)E*4);
  int*   etH   = (int*)  alloc((size_t)E*4);
  float* sA    = (float*)alloc((size_t)N*4);
  float* sB    = (float*)alloc((size_t)N*4);
  u16*   pbAll = (u16*)  alloc((size_t)2048*512*2);
  // contiguous zero region
  int*   cnt   = (int*)  alloc(4);
  float* topic = (float*)alloc((size_t)N*4);
  float* amask = (float*)alloc((size_t)N*4);
  int*   deghI = (int*)  alloc((size_t)N*4);
  int*   degiI = (int*)  alloc((size_t)N*4);
  (void)ws_size; (void)n_in; (void)out_size;

  size_t zbytes = (char*)(degiI + N) - (char*)cnt;
  hipMemsetAsync(cnt, 0, zbytes, stream);

  // packed-weight offsets (u16 units = frag*512)
  u16* pbWenc = pbAll + (size_t)0*512;
  u16* pbWmT0 = pbAll + (size_t)128*512;
  u16* pbWmT1 = pbAll + (size_t)256*512;
  u16* pbGU0  = pbAll + (size_t)384*512;
  u16* pbGU1  = pbAll + (size_t)896*512;
  u16* pbRelC = pbAll + (size_t)1408*512;
  u16* pbW1ht = pbAll + (size_t)1792*512;

  const float* tW = W1 + (size_t)(1024+2)*256;   // W1 rows 1026 (topic_h), 1027 (topic_t)

  // ---- weights: pack (+distW/encnt/bias2 tail), Wcomb, pack Wcomb ----
  k_packall<<<2055,64,0,stream>>>(W_enc, W_msg, W_gate, W_upd, W1, pbAll,
                                  dist_e, distW, nontext, encnt, q, b1, bias2);
  k_bgemm<512,8,0,true,1><<<dim3(8,8),256,0,stream>>>(W_out, nullptr, nullptr, BIGK1, pbW1ht, WcombF,
      nullptr,nullptr,nullptr,nullptr,nullptr,nullptr,nullptr, 256, 256);
  k_packf32<<<256,64,0,stream>>>(WcombF, pbWcomb);

  // ---- triple scores + top-32 (tri fused with blockmax + degree hist) ----
  int nb1 = CDIV(N,4);
  k_rowdot_all<<<nb1+CDIV(R,4),256,0,stream>>>(ent, nontext, q, qe, N, Ntext, rel, qr, R, nb1);
  int nbE = CDIV(E,256);
  k_tri<<<nbE,256,0,stream>>>(h_ids, r_ids, t_ids, qe, qr, tri, bmax, deghI, degiI, E);
  k_thresh<<<1,64,0,stream>>>(bmax, thrT, nbE);
  k_compact<<<nbE,256,0,stream>>>(tri, thrT, cnt, ci, cv, E);
  k_final32<<<1,64,0,stream>>>(ci, cv, cnt, ai, as, h_ids, t_ids, topicId, nTopic, topic, amask);

  // ---- CSR both directions ----
  int nb = CDIV(N,256);
  k_scan1<<<2*nb,256,0,stream>>>(degiI, deghI, offsT, offsH, bsum, N, nb);
  k_scan2two<<<1,256,0,stream>>>(bsum, nb);
  k_scan3<<<2*nb,256,0,stream>>>(offsT, offsH, bsum, curT, curH, N, nb);
  k_place<<<nbE,256,0,stream>>>(h_ids, r_ids, t_ids, curT, curH, ehr, eIdx, etH, E);

  // ---- DDE (paired fwd/rev rounds); round B also inits BFS dist ----
  int nbN4 = CDIV(N,4);
  k_dde2<<<dim3(nbN4,2),256,0,stream>>>(offsT, degiI, ehr, offsH, deghI, etH,
      topic, topic, sB, sA, pe4, 0, 2, nullptr, nullptr, N);
  k_dde2<<<dim3(nbN4,2),256,0,stream>>>(offsT, degiI, ehr, offsH, deghI, etH,
      sB, sA, nullptr, nullptr, pe4, 1, 3, amask, dA, N);

  // ---- bounded BFS (3 rounds, ping-pong dA->dB->dA->dB) ----
  k_bfs_g<<<nbN4,256,0,stream>>>(offsT, degiI, ehr, offsH, deghI, etH, dA, dB, N);
  k_bfs_g<<<nbN4,256,0,stream>>>(offsT, degiI, ehr, offsH, deghI, etH, dB, dA, N);
  k_bfs_g<<<nbN4,256,0,stream>>>(offsT, degiI, ehr, offsH, deghI, etH, dA, dB, N);

  // ---- relC = rel @ [WmB0 | WmB1 | W1r], bias2 folded into vrel cols ----
  k_bgemm<768,6,6,true,1><<<dim3(CDIV(R,32),6),256,0,stream>>>(rel, nullptr, nullptr, BIGK1, pbRelC, relC,
      bias2,nullptr,nullptr,nullptr,nullptr,nullptr,nullptr, R, 256);

  // ---- encoder (fused PE epilogue, bf16 h only; MR=2, CT=2) ----
  k_bgemm<256,2,3,true,2><<<dim3(CDIV(Ntext,64),2),256,0,stream>>>(ent, nullptr, nullptr, BIGK1, pbWenc, hB1,
      b_enc, W_enc, pe4, dB, topic, amask, distW, Ntext, 256);
  k_encnt_fill<<<N-Ntext,256,0,stream>>>(encnt, b_enc, W_enc, pe4, dB, topic, amask, distW, hB1, Ntext);

  // ---- 2-layer gated GNN (all-bf16 h; MR=2, CT=2 GEMMs) ----
  for (int l=0;l<2;l++){
    const u16* pT = l ? pbWmT1 : pbWmT0;
    const u16* pGU = l ? pbGU1 : pbGU0;
    u16* hinB  = l ? hB2 : hB1;
    u16* houtB = l ? hB1 : hB2;
    k_bgemm<256,2,1,false,2><<<dim3(CDIV(N,64),2),256,0,stream>>>(nullptr, hinB, nullptr, BIGK1, pT, hmB,
        nullptr,nullptr,nullptr,nullptr,nullptr,nullptr,nullptr, N, 256);
    k_agg<<<CDIV(N,4),256,0,stream>>>(offsT, degiI, ehr, hmB, relC, l*256, aggB, N);
    k_bgemm<512,2,4,false,2><<<dim3(CDIV(N,64),2),256,0,stream>>>(nullptr, hinB, aggB, 256, pGU, houtB,
        nullptr,nullptr,nullptr,nullptr,nullptr,nullptr,nullptr, N, 512);
  }

  // ---- UHT = h @ Wcomb, topic terms folded in epilogue (MR=2, CT=2) ----
  k_bgemm<512,2,5,false,2><<<dim3(CDIV(N,64),2),256,0,stream>>>(nullptr, hB1, nullptr, BIGK1, pbWcomb, UHT,
      tW,nullptr,nullptr,nullptr,topic,nullptr,nullptr, N, 256);

  // ---- final scorer (t-sorted CSR order) + anchor patch ----
  k_score<<<CDIV(N,4),256,0,stream>>>(offsT, degiI, ehr, eIdx, UHT, relC, W2, b2, out, N);
  k_patch<<<8,256,0,stream>>>(ai, as, h_ids, r_ids, t_ids, UHT, relC,
                              W1+(size_t)1024*256, W2, b2, out);
}

// Round 16
// 384.231 us; speedup vs baseline: 1.0352x; 1.0352x over previous
//
#include <hip/hip_runtime.h>
#include <math.h>

#define CDIV(a,b) (((a)+(b)-1)/(b))

typedef short short8 __attribute__((ext_vector_type(8)));
typedef float f32x4  __attribute__((ext_vector_type(4)));
typedef unsigned short u16;

__device__ __forceinline__ float warp_sum(float v){
  #pragma unroll
  for (int o=32;o;o>>=1) v += __shfl_down(v,o);
  return v;
}
__device__ __forceinline__ int warp_min(int v){
  #pragma unroll
  for (int o=32;o;o>>=1) v = min(v,__shfl_down(v,o));
  return v;
}
__device__ __forceinline__ u16 f2bf(float f){
  unsigned u = __float_as_uint(f);
  unsigned r = 0x7fffu + ((u>>16)&1u);
  return (u16)((u + r)>>16);
}
__device__ __forceinline__ float bl(u16 v){ return __uint_as_float(((unsigned)v)<<16); }

// ---------- fused row-dot (qe for entities, qr for relations) ----------
__global__ __launch_bounds__(256)
void k_rowdot_all(const float* __restrict__ ent, const float* __restrict__ nontext,
                  const float* __restrict__ q, float* __restrict__ qe,
                  int N, int Ntext,
                  const float* __restrict__ rel, float* __restrict__ qr, int R, int nb1){
  int wid = threadIdx.x>>6, lane = threadIdx.x&63;
  const float* src; float* dst; int row;
  if ((int)blockIdx.x < nb1){
    row = blockIdx.x*4 + wid; if (row >= N) return;
    src = (row < Ntext) ? (ent + (size_t)row*256) : nontext;
    dst = qe;
  } else {
    row = (blockIdx.x-nb1)*4 + wid; if (row >= R) return;
    src = rel + (size_t)row*256;
    dst = qr;
  }
  float4 a = *(const float4*)(src + lane*4);
  float4 b = *(const float4*)(q + lane*4);
  float s = a.x*b.x + a.y*b.y + a.z*b.z + a.w*b.w;
  s = warp_sum(s);
  if (!lane) dst[row] = s;
}

// ---------- tri + per-block max + degree hist (fused) ----------
__global__ __launch_bounds__(256)
void k_tri(const int* __restrict__ h, const int* __restrict__ r,
           const int* __restrict__ t, const float* __restrict__ qe,
           const float* __restrict__ qr, float* __restrict__ tri,
           float* __restrict__ bmax, int* __restrict__ degh, int* __restrict__ degi, int E){
  __shared__ float red[256];
  int e = blockIdx.x*256 + threadIdx.x;
  float v = -INFINITY;
  if (e < E){
    int hh=h[e], rr=r[e], tt=t[e];
    v = qe[hh] + qr[rr] + qe[tt];
    tri[e] = v;
    atomicAdd(&degh[hh], 1);
    atomicAdd(&degi[tt], 1);
  }
  red[threadIdx.x]=v; __syncthreads();
  for (int s=128;s;s>>=1){ if ((int)threadIdx.x<s) red[threadIdx.x]=fmaxf(red[threadIdx.x],red[threadIdx.x+s]); __syncthreads(); }
  if (!threadIdx.x) bmax[blockIdx.x]=red[0];
}

// ---------- 32nd-largest of block maxes: single wave, no barriers ----------
__global__ __launch_bounds__(64)
void k_thresh(const float* __restrict__ bmax, float* __restrict__ thrT, int nb){
  int lane = threadIdx.x;
  float m = -INFINITY;
  for (int i=lane; i<nb; i+=64) m = fmaxf(m, bmax[i]);
  for (int it=0; it<32; it++){
    float bv = m; int bln = lane;
    #pragma unroll
    for (int o=32;o;o>>=1){
      float ov = __shfl_down(bv,o);
      int   ol = __shfl_down(bln,o);
      if (ov>bv){ bv=ov; bln=ol; }
    }
    float mv = __shfl(bv,0);
    int   wl = __shfl(bln,0);
    if (lane==wl) m = -INFINITY;
    if (it==31 && lane==0) thrT[0]=mv;
  }
}

__global__ void k_compact(const float* __restrict__ tri, const float* __restrict__ thrT,
                          int* __restrict__ cnt, int* __restrict__ ci, float* __restrict__ cv, int E){
  int e = blockIdx.x*256 + threadIdx.x; if (e>=E) return;
  float v = tri[e];
  if (v >= thrT[0]){
    int p = atomicAdd(cnt, 1);
    ci[p]=e; cv[p]=v;
  }
}

// ---------- final top-32 + masks: single wave, NO per-lane arrays ----------
__global__ __launch_bounds__(64)
void k_final32(const int* __restrict__ ci, const float* __restrict__ cv, const int* __restrict__ cnt,
               int* __restrict__ ai, float* __restrict__ as,
               const int* __restrict__ h_ids, const int* __restrict__ t_ids,
               const int* __restrict__ topicId, int nTopic,
               float* __restrict__ topic, float* __restrict__ amask){
  int lane = threadIdx.x;
  int C = *cnt; if (C > 1024) C = 1024;
  int nIter = CDIV(C,64);
  unsigned selMask = 0;
  int myai=0; float myas=0.f;
  for (int it=0; it<32; it++){
    float bv=-INFINITY; int bi=0x7fffffff; int bj=-1;
    for (int j=0;j<nIter;j++){
      int p = lane + j*64;
      if (p < C && !((selMask>>j)&1u)){
        float v = cv[p]; int idx = ci[p];
        if (v>bv || (v==bv && idx<bi)){ bv=v; bi=idx; bj=j; }
      }
    }
    int bln = lane;
    #pragma unroll
    for (int o=32;o;o>>=1){
      float ov=__shfl_down(bv,o); int oi=__shfl_down(bi,o);
      int   oj=__shfl_down(bj,o); int ol=__shfl_down(bln,o);
      if (ov>bv || (ov==bv && oi<bi)){ bv=ov; bi=oi; bj=oj; bln=ol; }
    }
    float wv=__shfl(bv,0); int wi=__shfl(bi,0);
    int   wj=__shfl(bj,0); int wl=__shfl(bln,0);
    if (lane==wl) selMask |= (1u<<wj);
    if (lane==it){ myai=wi; myas=wv; }
  }
  if (lane<32){
    ai[lane]=myai; as[lane]=myas;
    int e = myai;
    amask[h_ids[e]]=1.f;
    amask[t_ids[e]]=1.f;
  }
  if (lane<nTopic) topic[topicId[lane]]=1.f;
}

// ---------- CSR build (both directions, fused scans) ----------
__global__ void k_scan1(const int* __restrict__ degT, const int* __restrict__ degH,
                        int* __restrict__ offsT, int* __restrict__ offsH,
                        int* __restrict__ bsum, int N, int nb){
  __shared__ int s[256];
  int which = (int)blockIdx.x >= nb;
  int b = which ? blockIdx.x - nb : blockIdx.x;
  const int* deg = which ? degH : degT;
  int* offs = which ? offsH : offsT;
  int i = b*256 + threadIdx.x;
  int v = (i<N) ? deg[i] : 0;
  s[threadIdx.x] = v; __syncthreads();
  #pragma unroll
  for (int o=1;o<256;o<<=1){
    int add = (threadIdx.x>=(unsigned)o) ? s[threadIdx.x-o] : 0; __syncthreads();
    s[threadIdx.x] += add; __syncthreads();
  }
  if (i<N) offs[i] = s[threadIdx.x] - v;
  if (threadIdx.x==255) bsum[blockIdx.x] = s[255];
}
__global__ void k_scan2two(int* __restrict__ bsum, int nb){
  __shared__ int s[256];
  int t=threadIdx.x;
  int half = t>>7, idx = t&127;
  int v = (idx<nb)? bsum[half*nb+idx] : 0;
  s[t]=v; __syncthreads();
  #pragma unroll
  for (int o=1;o<128;o<<=1){ int add=(idx>=o)?s[t-o]:0; __syncthreads(); s[t]+=add; __syncthreads(); }
  if (idx<nb) bsum[half*nb+idx] = s[t]-v;
}
__global__ void k_scan3(int* __restrict__ offsT, int* __restrict__ offsH,
                        const int* __restrict__ bsum,
                        int* __restrict__ curT, int* __restrict__ curH, int N, int nb){
  int which = (int)blockIdx.x >= nb;
  int b = which ? blockIdx.x - nb : blockIdx.x;
  int i = b*256+threadIdx.x; if (i>=N) return;
  int* offs = which ? offsH : offsT;
  int* cur  = which ? curH  : curT;
  int o = offs[i] + bsum[blockIdx.x];
  offs[i]=o; cur[i]=o;
}
__global__ void k_place(const int* __restrict__ h, const int* __restrict__ r,
                        const int* __restrict__ t,
                        int* __restrict__ curT, int* __restrict__ curH,
                        int2* __restrict__ ehr, int* __restrict__ eIdx,
                        int* __restrict__ etH, int E){
  int e = blockIdx.x*256+threadIdx.x; if (e>=E) return;
  int hh=h[e], tt=t[e];
  int pos = atomicAdd(&curT[tt], 1);
  ehr[pos] = make_int2(hh, r[e]);
  eIdx[pos] = e;
  int posh = atomicAdd(&curH[hh], 1);
  etH[posh] = tt;
}

// ---------- DDE pair (grid.y: 0 = T-direction, 1 = H-direction) ----------
__global__ __launch_bounds__(256)
void k_dde2(const int* __restrict__ offsT, const int* __restrict__ degT, const int2* __restrict__ ehr,
            const int* __restrict__ offsH, const int* __restrict__ degH, const int* __restrict__ etH,
            const float* __restrict__ s0, const float* __restrict__ s1,
            float* __restrict__ sn0, float* __restrict__ sn1,
            float* __restrict__ pe4, int c0, int c1,
            const float* __restrict__ amask, int* __restrict__ dist0, int N){
  int wid=threadIdx.x>>6, lane=threadIdx.x&63;
  int i = blockIdx.x*4+wid; if (i>=N) return;
  int dir = blockIdx.y;
  const int* offs = dir ? offsH : offsT;
  const int* deg  = dir ? degH  : degT;
  const float* s  = dir ? s1 : s0;
  float* sn       = dir ? sn1 : sn0;
  int col         = dir ? c1 : c0;
  int start=offs[i], cnt=deg[i];
  float a=0.f;
  if (dir){
    for (int k=lane;k<cnt;k+=64) a += s[etH[start+k]];
  } else {
    for (int k=lane;k<cnt;k+=64) a += s[ehr[start+k].x];
  }
  a = warp_sum(a);
  if (!lane){
    float v = a / fmaxf((float)cnt,1.f);
    if (sn) sn[i]=v;
    pe4[i*4+col]=v;
    if (dist0 && !dir) dist0[i] = (amask[i]>0.f)?0:4;
  }
}

// ---------- BFS via CSR gather ----------
__global__ __launch_bounds__(256)
void k_bfs_g(const int* __restrict__ offsT, const int* __restrict__ degT, const int2* __restrict__ ehr,
             const int* __restrict__ offsH, const int* __restrict__ degH, const int* __restrict__ etH,
             const int* __restrict__ din, int* __restrict__ dout, int N){
  int wid=threadIdx.x>>6, lane=threadIdx.x&63;
  int i = blockIdx.x*4+wid; if (i>=N) return;
  int sT=offsT[i], cT=degT[i];
  int sH=offsH[i], cH=degH[i];
  int best = 4;
  for (int k=lane;k<cT;k+=64) best = min(best, din[ehr[sT+k].x]+1);
  for (int k=lane;k<cH;k+=64) best = min(best, din[etH[sH+k]]+1);
  best = warp_min(best);
  if (!lane) dout[i] = min(din[i], best);
}

// ---------- fused small dense (distW rows 0-4, encnt, bias2) ----------
__global__ void k_smalls(const float* __restrict__ dist_e, const float* __restrict__ W_enc,
                         float* __restrict__ distW,
                         const float* __restrict__ nontext, float* __restrict__ encnt,
                         const float* __restrict__ q, const float* __restrict__ W1,
                         const float* __restrict__ b1, float* __restrict__ bias2){
  int b = blockIdx.x, j = threadIdx.x;
  if (b < 5){
    const float* Wpe = W_enc + (256+4)*256;
    float s=0.f;
    #pragma unroll
    for (int p=0;p<16;p++) s += dist_e[b*16+p]*Wpe[p*256+j];
    distW[b*256+j]=s;
  } else if (b == 5){
    float s=0.f;
    for (int k=0;k<256;k++) s += nontext[k]*W_enc[k*256+j];
    encnt[j]=s;
  } else {
    float s=b1[j];
    for (int k=0;k<256;k++) s += q[k]*W1[k*256+j];
    bias2[j]=s;
  }
}

// ---------- fused weight pack -> bf16 MFMA frag order ----------
__global__ __launch_bounds__(64)
void k_packall(const float* __restrict__ W_enc, const float* __restrict__ W_msg,
               const float* __restrict__ W_gate, const float* __restrict__ W_upd,
               const float* __restrict__ W1, u16* __restrict__ pbAll){
  int f = blockIdx.x, lane = threadIdx.x;
  int tgt, fid, nt16;
  if      (f < 128) { tgt=0; fid=f;      nt16=16; }
  else if (f < 256) { tgt=1; fid=f-128;  nt16=16; }
  else if (f < 384) { tgt=2; fid=f-256;  nt16=16; }
  else if (f < 896) { tgt=3; fid=f-384;  nt16=32; }
  else if (f < 1408){ tgt=4; fid=f-896;  nt16=32; }
  else if (f < 1792){ tgt=5; fid=f-1408; nt16=48; }
  else              { tgt=6; fid=f-1792; nt16=32; }
  int ks = fid/nt16, nt = fid%nt16;
  int kb = ks*32 + 8*(lane>>4);
  int n  = nt*16 + (lane&15);
  u16 v[8];
  #pragma unroll
  for (int i=0;i<8;i++){
    int k = kb+i;
    float x;
    if (tgt==0) x = W_enc[(size_t)k*256+n];
    else if (tgt==1) x = W_msg[(size_t)k*256+n];
    else if (tgt==2) x = W_msg[(size_t)(512+k)*256+n];
    else if (tgt==3 || tgt==4){
      const float* Wg = W_gate + (tgt==4 ? (size_t)512*256 : 0);
      const float* Wu = W_upd  + (tgt==4 ? (size_t)256*256 : 0);
      int blk = n>>4, c = ((blk>>1)<<4) | (n&15);
      if ((blk&1)==0) x = Wg[(size_t)k*256+c];
      else            x = (k<256) ? 0.f : Wu[(size_t)(k-256)*256+c];
    }
    else if (tgt==5){
      if (n<256)      x = W_msg[(size_t)(256+k)*256+n];
      else if (n<512) x = W_msg[(size_t)(768+k)*256+(n-256)];
      else            x = W1[(size_t)(512+k)*256+(n-512)];
    } else {
      if (n<256) x = W1[(size_t)(256+k)*256+n];
      else       x = W1[(size_t)(768+k)*256+(n-256)];
    }
    v[i]=f2bf(x);
  }
  *(uint4*)(pbAll + ((size_t)f*64+lane)*8) = *(uint4*)v;
}

// pack fp32 [256][512] -> 256 frags
__global__ __launch_bounds__(64)
void k_packf32(const float* __restrict__ W, u16* __restrict__ Bp){
  int f = blockIdx.x, lane = threadIdx.x;
  int ks = f/32, nt = f%32;
  int kb = ks*32 + 8*(lane>>4);
  int n  = nt*16 + (lane&15);
  u16 v[8];
  #pragma unroll
  for (int i=0;i<8;i++) v[i] = f2bf(W[(size_t)(kb+i)*512 + n]);
  *(uint4*)(Bp + ((size_t)f*64+lane)*8) = *(uint4*)v;
}

// ---------- MFMA bf16 GEMM (column-split via grid.y = CT; MR row-frags/wave) ----------
template<int NCOLS, int CT, int MODE, bool AF32, int MR>
__global__ __launch_bounds__(256)
void k_bgemm(const float* __restrict__ A1f, const u16* __restrict__ A2a,
             const u16* __restrict__ A2b, int K1,
             const u16* __restrict__ Bp, void* __restrict__ Cout,
             const float* __restrict__ xb, const float* __restrict__ W_enc,
             const float* __restrict__ pe4, const int* __restrict__ dist,
             const float* __restrict__ topic, const float* __restrict__ amask,
             const float* __restrict__ distW,
             int M, int K)
{
  constexpr int NT16 = NCOLS/16;
  constexpr int CPB  = NCOLS/CT;
  constexpr int NREP = CPB/32;
  const int tid  = threadIdx.x;
  const int lane = tid & 63;
  const int w    = tid >> 6;
  const int wr   = w >> 1, wc = w & 1;
  const int ct   = blockIdx.y;
  const int row0 = (blockIdx.x*2 + wr)*(16*MR);
  const int lrow = lane & 15;
  const int kc   = lane >> 4;
  int arow[MR];
  #pragma unroll
  for (int m=0;m<MR;m++){
    int rr = row0 + m*16 + lrow;
    arow[m] = (rr >= M) ? M-1 : rr;
  }

  f32x4 acc[MR][NREP];
  #pragma unroll
  for (int m=0;m<MR;m++)
    #pragma unroll
    for (int n=0;n<NREP;n++) acc[m][n] = (f32x4){0.f,0.f,0.f,0.f};

  const int ksteps = K/32;
  const int fcolBase = ct*(CPB/16) + wc*NREP;

  auto do_step = [&](short8* af, int ks){
    const u16* bp = Bp + ((size_t)(ks*NT16 + fcolBase)*64 + lane)*8;
    #pragma unroll
    for (int n=0;n<NREP;n++){
      short8 bf = *(const short8*)(bp + (size_t)n*64*8);
      #pragma unroll
      for (int m=0;m<MR;m++)
        acc[m][n] = __builtin_amdgcn_mfma_f32_16x16x32_bf16(af[m], bf, acc[m][n], 0, 0, 0);
    }
  };

  if (AF32){
    for (int ks=0; ks<ksteps; ks++){
      short8 af[MR];
      #pragma unroll
      for (int m=0;m<MR;m++){
        const float* ap = A1f + (size_t)arow[m]*256 + ks*32 + kc*8;
        float4 a0 = *(const float4*)ap;
        float4 a1 = *(const float4*)(ap+4);
        af[m][0]=(short)f2bf(a0.x); af[m][1]=(short)f2bf(a0.y); af[m][2]=(short)f2bf(a0.z); af[m][3]=(short)f2bf(a0.w);
        af[m][4]=(short)f2bf(a1.x); af[m][5]=(short)f2bf(a1.y); af[m][6]=(short)f2bf(a1.z); af[m][7]=(short)f2bf(a1.w);
      }
      do_step(af, ks);
    }
  } else {
    int s1 = K1>>5; if (s1 > ksteps) s1 = ksteps;
    for (int ks=0; ks<s1; ks++){
      short8 af[MR];
      #pragma unroll
      for (int m=0;m<MR;m++)
        af[m] = *(const short8*)(A2a + (size_t)arow[m]*256 + ks*32 + kc*8);
      do_step(af, ks);
    }
    for (int ks=s1; ks<ksteps; ks++){
      short8 af[MR];
      #pragma unroll
      for (int m=0;m<MR;m++)
        af[m] = *(const short8*)(A2b + (size_t)arow[m]*256 + (ks-s1)*32 + kc*8);
      do_step(af, ks);
    }
  }

  #pragma unroll
  for (int m=0;m<MR;m++){
    #pragma unroll
    for (int r=0;r<4;r++){
      int orow = row0 + m*16 + 4*kc + r;
      if (orow >= M) continue;
      if (MODE==0 || MODE==1){
        #pragma unroll
        for (int n=0;n<NREP;n++){
          int col = ct*CPB + wc*(CPB/2) + n*16 + lrow;
          float v = acc[m][n][r];
          if (MODE==0) ((float*)Cout)[(size_t)orow*NCOLS + col] = v;
          else         ((u16*)Cout)[(size_t)orow*NCOLS + col] = f2bf(v);
        }
      } else if (MODE==5){
        float tp = topic[orow];
        #pragma unroll
        for (int n=0;n<NREP;n++){
          int col = ct*CPB + wc*(CPB/2) + n*16 + lrow;
          float v = acc[m][n][r] + tp*xb[col];
          ((u16*)Cout)[(size_t)orow*NCOLS + col] = f2bf(v);
        }
      } else if (MODE==6){
        #pragma unroll
        for (int n=0;n<NREP;n++){
          int col = ct*CPB + wc*(CPB/2) + n*16 + lrow;
          float v = acc[m][n][r];
          if (col >= 512) v += xb[col-512];
          ((u16*)Cout)[(size_t)orow*NCOLS + col] = f2bf(v);
        }
      } else if (MODE==3){
        float p0=pe4[orow*4+0], p1=pe4[orow*4+1], p2=pe4[orow*4+2], p3=pe4[orow*4+3];
        int dd=dist[orow];
        float tp=topic[orow], am=amask[orow];
        const float* Wpe = W_enc + 256*256;
        #pragma unroll
        for (int n=0;n<NREP;n++){
          int col = ct*CPB + wc*(CPB/2) + n*16 + lrow;
          float v = acc[m][n][r];
          v += xb[col] + Wpe[22*256+col]
             + p0*Wpe[col] + p1*Wpe[256+col] + p2*Wpe[512+col] + p3*Wpe[768+col]
             + distW[dd*256+col] + tp*Wpe[20*256+col] + am*Wpe[21*256+col];
          ((u16*)Cout)[(size_t)orow*256 + col] = f2bf(fmaxf(v, 0.f));
        }
      } else { // MODE 4
        #pragma unroll
        for (int k=0;k<NREP/2;k++){
          int col = (ct*(CPB/32) + wc*(CPB/64) + k)*16 + lrow;
          size_t idx = (size_t)orow*256 + col;
          float g = 1.f/(1.f+expf(-acc[m][2*k][r]));
          float u = tanhf(acc[m][2*k+1][r]);
          float v = bl(A2a[idx]) + g*u;
          ((u16*)Cout)[idx] = f2bf(v);
        }
      }
    }
  }
}

// ---------- non-text rows of encoder ----------
__global__ __launch_bounds__(256)
void k_encnt_fill(const float* __restrict__ encnt, const float* __restrict__ b_enc,
                  const float* __restrict__ W_enc, const float* __restrict__ pe4,
                  const int* __restrict__ dist, const float* __restrict__ topic,
                  const float* __restrict__ amask, const float* __restrict__ distW,
                  u16* __restrict__ hB, int Ntext){
  int i = Ntext + blockIdx.x, j = threadIdx.x;
  const float* Wpe = W_enc + 256*256;
  float p0=pe4[i*4+0], p1=pe4[i*4+1], p2=pe4[i*4+2], p3=pe4[i*4+3];
  int d = dist[i];
  float tp = topic[i], am = amask[i];
  float v = encnt[j] + b_enc[j] + Wpe[22*256+j]
          + p0*Wpe[j] + p1*Wpe[256+j] + p2*Wpe[512+j] + p3*Wpe[768+j]
          + distW[d*256+j] + tp*Wpe[20*256+j] + am*Wpe[21*256+j];
  hB[(size_t)i*256+j] = f2bf(fmaxf(v, 0.f));
}

// ---------- GNN aggregation: wave per node, 4 cols/lane, 4x unroll ----------
__global__ __launch_bounds__(256)
void k_agg(const int* __restrict__ offs, const int* __restrict__ degi,
           const int2* __restrict__ ehr,
           const u16* __restrict__ hm, const u16* __restrict__ relC, int colOff,
           u16* __restrict__ agg, int N){
  int wid = threadIdx.x>>6, lane = threadIdx.x&63;
  int i = blockIdx.x*4 + wid; if (i>=N) return;
  int start = offs[i], cnt = degi[i];
  int c4 = lane*4;
  float a0=0.f,a1=0.f,a2=0.f,a3=0.f;
  int k=0;
  for (; k+3<cnt; k+=4){
    int2 hr[4]; uint2 ua[4], ub[4];
    #pragma unroll
    for (int j=0;j<4;j++) hr[j] = ehr[start+k+j];
    #pragma unroll
    for (int j=0;j<4;j++){
      ua[j] = *(const uint2*)(hm + (size_t)hr[j].x*256 + c4);
      ub[j] = *(const uint2*)(relC + (size_t)hr[j].y*768 + colOff + c4);
    }
    #pragma unroll
    for (int j=0;j<4;j++){
      a0 += fmaxf(bl((u16)(ua[j].x&0xffff))+bl((u16)(ub[j].x&0xffff)),0.f);
      a1 += fmaxf(bl((u16)(ua[j].x>>16))  +bl((u16)(ub[j].x>>16)),  0.f);
      a2 += fmaxf(bl((u16)(ua[j].y&0xffff))+bl((u16)(ub[j].y&0xffff)),0.f);
      a3 += fmaxf(bl((u16)(ua[j].y>>16))  +bl((u16)(ub[j].y>>16)),  0.f);
    }
  }
  for (; k<cnt; k++){
    int2 hr = ehr[start+k];
    uint2 ua = *(const uint2*)(hm + (size_t)hr.x*256 + c4);
    uint2 ub = *(const uint2*)(relC + (size_t)hr.y*768 + colOff + c4);
    a0 += fmaxf(bl((u16)(ua.x&0xffff))+bl((u16)(ub.x&0xffff)),0.f);
    a1 += fmaxf(bl((u16)(ua.x>>16))  +bl((u16)(ub.x>>16)),  0.f);
    a2 += fmaxf(bl((u16)(ua.y&0xffff))+bl((u16)(ub.y&0xffff)),0.f);
    a3 += fmaxf(bl((u16)(ua.y>>16))  +bl((u16)(ub.y>>16)),  0.f);
  }
  uint2 o;
  o.x = (unsigned)f2bf(a0) | ((unsigned)f2bf(a1)<<16);
  o.y = (unsigned)f2bf(a2) | ((unsigned)f2bf(a3)<<16);
  *(uint2*)(agg + (size_t)i*256 + c4) = o;
}

// ---------- scorer: wave per node (t-sorted), topic+bias2 pre-folded, 4x unroll ----------
__global__ __launch_bounds__(256)
void k_score(const int* __restrict__ offs, const int* __restrict__ degi,
             const int2* __restrict__ ehr, const int* __restrict__ eIdx,
             const u16* __restrict__ UHT, const u16* __restrict__ relC,
             const float* __restrict__ W2,
             const float* __restrict__ b2, float* __restrict__ out, int N){
  int wid = threadIdx.x>>6, lane = threadIdx.x&63;
  int i = blockIdx.x*4 + wid; if (i>=N) return;
  int start = offs[i], cnt = degi[i];
  if (!cnt) return;
  int c = lane*4;
  uint2 ud = *(const uint2*)(UHT + (size_t)i*512 + 256 + c);
  float b0 = bl((u16)(ud.x&0xffff)), b1v = bl((u16)(ud.x>>16));
  float b2v= bl((u16)(ud.y&0xffff)), b3  = bl((u16)(ud.y>>16));
  float4 w = *(const float4*)(W2 + c);
  float bout = b2[0];
  int k=0;
  for (; k+3<cnt; k+=4){
    int2 e[4]; uint2 ua[4], ub[4];
    #pragma unroll
    for (int j=0;j<4;j++) e[j] = ehr[start+k+j];
    #pragma unroll
    for (int j=0;j<4;j++){
      ua[j] = *(const uint2*)(UHT + (size_t)e[j].x*512 + c);
      ub[j] = *(const uint2*)(relC + (size_t)e[j].y*768 + 512 + c);
    }
    float p[4];
    #pragma unroll
    for (int j=0;j<4;j++){
      p[j] = fmaxf(b0 + bl((u16)(ua[j].x&0xffff)) + bl((u16)(ub[j].x&0xffff)),0.f)*w.x
           + fmaxf(b1v+ bl((u16)(ua[j].x>>16))    + bl((u16)(ub[j].x>>16)),  0.f)*w.y
           + fmaxf(b2v+ bl((u16)(ua[j].y&0xffff)) + bl((u16)(ub[j].y&0xffff)),0.f)*w.z
           + fmaxf(b3 + bl((u16)(ua[j].y>>16))    + bl((u16)(ub[j].y>>16)),  0.f)*w.w;
    }
    #pragma unroll
    for (int j=0;j<4;j++) p[j] = warp_sum(p[j]);
    if (!lane){
      #pragma unroll
      for (int j=0;j<4;j++) out[eIdx[start+k+j]] = p[j] + bout;
    }
  }
  for (; k<cnt; k++){
    int2 e0 = ehr[start+k];
    uint2 ua = *(const uint2*)(UHT + (size_t)e0.x*512 + c);
    uint2 ub = *(const uint2*)(relC + (size_t)e0.y*768 + 512 + c);
    float p = fmaxf(b0 + bl((u16)(ua.x&0xffff)) + bl((u16)(ub.x&0xffff)),0.f)*w.x
            + fmaxf(b1v+ bl((u16)(ua.x>>16))    + bl((u16)(ub.x>>16)),  0.f)*w.y
            + fmaxf(b2v+ bl((u16)(ua.y&0xffff)) + bl((u16)(ub.y&0xffff)),0.f)*w.z
            + fmaxf(b3 + bl((u16)(ua.y>>16))    + bl((u16)(ub.y>>16)),  0.f)*w.w;
    p = warp_sum(p);
    if (!lane) out[eIdx[start+k]] = p + bout;
  }
}

// ---------- anchor patch (32 edges; topic+bias2 already folded in tables) ----------
__global__ __launch_bounds__(256)
void k_patch(const int* __restrict__ ai, const float* __restrict__ as,
             const int* __restrict__ h_ids, const int* __restrict__ r_ids, const int* __restrict__ t_ids,
             const u16* __restrict__ UHT, const u16* __restrict__ relC,
             const float* __restrict__ W1s, const float* __restrict__ W2,
             const float* __restrict__ b2, float* __restrict__ out){
  int wid = threadIdx.x>>6, lane = threadIdx.x&63;
  int k = blockIdx.x*4 + wid; if (k>=32) return;
  int e = ai[k];
  int h=h_ids[e], r=r_ids[e], t=t_ids[e];
  float aS = as[k];
  int c = lane*4;
  uint2 ua = *(const uint2*)(UHT + (size_t)h*512 + c);
  uint2 ud = *(const uint2*)(UHT + (size_t)t*512 + 256 + c);
  uint2 ub = *(const uint2*)(relC + (size_t)r*768 + 512 + c);
  float4 w0 = *(const float4*)(W1s + 0*256 + c);
  float4 w1 = *(const float4*)(W1s + 1*256 + c);
  float4 acc;
  acc.x = bl((u16)(ua.x&0xffff))+bl((u16)(ub.x&0xffff))+bl((u16)(ud.x&0xffff)) + w0.x + aS*w1.x;
  acc.y = bl((u16)(ua.x>>16))  +bl((u16)(ub.x>>16))  +bl((u16)(ud.x>>16))   + w0.y + aS*w1.y;
  acc.z = bl((u16)(ua.y&0xffff))+bl((u16)(ub.y&0xffff))+bl((u16)(ud.y&0xffff)) + w0.z + aS*w1.z;
  acc.w = bl((u16)(ua.y>>16))  +bl((u16)(ub.y>>16))  +bl((u16)(ud.y>>16))   + w0.w + aS*w1.w;
  acc.x=fmaxf(acc.x,0.f); acc.y=fmaxf(acc.y,0.f); acc.z=fmaxf(acc.z,0.f); acc.w=fmaxf(acc.w,0.f);
  float4 w = *(const float4*)(W2 + c);
  float p = acc.x*w.x + acc.y*w.y + acc.z*w.z + acc.w*w.w;
  p = warp_sum(p);
  if (!lane) out[e] = p + b2[0];
}

// ---------- host ----------
extern "C" void kernel_launch(void* const* d_in, const int* in_sizes, int n_in,
                              void* d_out, int out_size, void* d_ws, size_t ws_size,
                              hipStream_t stream)
{
  const int*   h_ids   = (const int*)d_in[0];
  const int*   r_ids   = (const int*)d_in[1];
  const int*   t_ids   = (const int*)d_in[2];
  const float* q       = (const float*)d_in[3];
  const float* ent     = (const float*)d_in[4];
  const float* rel     = (const float*)d_in[5];
  const int*   topicId = (const int*)d_in[6];
  const float* nontext = (const float*)d_in[9];
  const float* dist_e  = (const float*)d_in[10];
  const float* W_enc   = (const float*)d_in[11];
  const float* b_enc   = (const float*)d_in[12];
  const float* W_msg   = (const float*)d_in[13];
  const float* W_gate  = (const float*)d_in[14];
  const float* W_upd   = (const float*)d_in[15];
  const float* W_out   = (const float*)d_in[16];
  const float* W1      = (const float*)d_in[17];
  const float* b1      = (const float*)d_in[18];
  const float* W2      = (const float*)d_in[19];
  const float* b2      = (const float*)d_in[20];
  float* out = (float*)d_out;

  const int E = in_sizes[0];
  const int Ntext = in_sizes[4]/256;
  const int R = in_sizes[5]/256;
  const int NT = 500;
  const int N = Ntext + NT;
  const int nTopic = in_sizes[6];
  const int BIGK1 = 1<<28;

  char* ws = (char*)d_ws;
  size_t off = 0;
  auto alloc = [&](size_t bytes)->void*{
    size_t o = (off + 255) & ~(size_t)255;
    off = o + bytes;
    return (void*)(ws + o);
  };
  // big activations (all-bf16 h)
  u16*   hB1   = (u16*)  alloc((size_t)N*256*2);
  u16*   hB2   = (u16*)  alloc((size_t)N*256*2);
  u16*   hmB   = (u16*)  alloc((size_t)N*256*2);
  u16*   aggB  = (u16*)  alloc((size_t)N*256*2);
  u16*   relC  = (u16*)  alloc((size_t)R*768*2);
  u16*   UHT   = (u16*)  alloc((size_t)N*512*2);
  float* WcombF= (float*)alloc((size_t)256*512*4);
  u16*   pbWcomb=(u16*)  alloc((size_t)256*512*2);
  // small
  float* qe    = (float*)alloc((size_t)N*4);
  float* qr    = (float*)alloc((size_t)R*4);
  float* tri   = (float*)alloc((size_t)E*4);
  float* bmax  = (float*)alloc(1024*4);
  float* thrT  = (float*)alloc(4);
  int*   ci    = (int*)  alloc((size_t)E*4);
  float* cv    = (float*)alloc((size_t)E*4);
  int*   ai    = (int*)  alloc(32*4);
  float* as    = (float*)alloc(32*4);
  float* pe4   = (float*)alloc((size_t)N*16);
  int*   dA    = (int*)  alloc((size_t)N*4);
  int*   dB    = (int*)  alloc((size_t)N*4);
  float* distW = (float*)alloc(5*256*4);
  float* encnt = (float*)alloc(256*4);
  float* bias2 = (float*)alloc(256*4);
  int*   offsT = (int*)  alloc((size_t)N*4);
  int*   offsH = (int*)  alloc((size_t)N*4);
  int*   bsum  = (int*)  alloc(256*4);
  int*   curT  = (int*)  alloc((size_t)N*4);
  int*   curH  = (int*)  alloc((size_t)N*4);
  int2*  ehr   = (int2*) alloc((size_t)E*8);
  int*   eIdx  = (int*)  alloc((size_t)E*4);
  int*   etH   = (int*)  alloc((size_t)E*4);
  float* sA    = (float*)alloc((size_t)N*4);
  float* sB    = (float*)alloc((size_t)N*4);
  u16*   pbAll = (u16*)  alloc((size_t)2048*512*2);
  // contiguous zero region
  int*   cnt   = (int*)  alloc(4);
  float* topic = (float*)alloc((size_t)N*4);
  float* amask = (float*)alloc((size_t)N*4);
  int*   deghI = (int*)  alloc((size_t)N*4);
  int*   degiI = (int*)  alloc((size_t)N*4);
  (void)ws_size; (void)n_in; (void)out_size;

  size_t zbytes = (char*)(degiI + N) - (char*)cnt;
  hipMemsetAsync(cnt, 0, zbytes, stream);

  // packed-weight offsets (u16 units = frag*512)
  u16* pbWenc = pbAll + (size_t)0*512;
  u16* pbWmT0 = pbAll + (size_t)128*512;
  u16* pbWmT1 = pbAll + (size_t)256*512;
  u16* pbGU0  = pbAll + (size_t)384*512;
  u16* pbGU1  = pbAll + (size_t)896*512;
  u16* pbRelC = pbAll + (size_t)1408*512;
  u16* pbW1ht = pbAll + (size_t)1792*512;

  const float* tW = W1 + (size_t)(1024+2)*256;   // W1 rows 1026 (topic_h), 1027 (topic_t)

  // ---- weights: pack, Wcomb = W_out @ [W1h|W1t], pack Wcomb ----
  k_packall<<<2048,64,0,stream>>>(W_enc, W_msg, W_gate, W_upd, W1, pbAll);
  k_bgemm<512,8,0,true,1><<<dim3(8,8),256,0,stream>>>(W_out, nullptr, nullptr, BIGK1, pbW1ht, WcombF,
      nullptr,nullptr,nullptr,nullptr,nullptr,nullptr,nullptr, 256, 256);
  k_packf32<<<256,64,0,stream>>>(WcombF, pbWcomb);

  // ---- triple scores + top-32 (tri fused with blockmax + degree hist) ----
  int nb1 = CDIV(N,4);
  k_rowdot_all<<<nb1+CDIV(R,4),256,0,stream>>>(ent, nontext, q, qe, N, Ntext, rel, qr, R, nb1);
  int nbE = CDIV(E,256);
  k_tri<<<nbE,256,0,stream>>>(h_ids, r_ids, t_ids, qe, qr, tri, bmax, deghI, degiI, E);
  k_thresh<<<1,64,0,stream>>>(bmax, thrT, nbE);
  k_compact<<<nbE,256,0,stream>>>(tri, thrT, cnt, ci, cv, E);
  k_final32<<<1,64,0,stream>>>(ci, cv, cnt, ai, as, h_ids, t_ids, topicId, nTopic, topic, amask);

  // ---- CSR both directions ----
  int nb = CDIV(N,256);
  k_scan1<<<2*nb,256,0,stream>>>(degiI, deghI, offsT, offsH, bsum, N, nb);
  k_scan2two<<<1,256,0,stream>>>(bsum, nb);
  k_scan3<<<2*nb,256,0,stream>>>(offsT, offsH, bsum, curT, curH, N, nb);
  k_place<<<nbE,256,0,stream>>>(h_ids, r_ids, t_ids, curT, curH, ehr, eIdx, etH, E);

  // ---- DDE (paired fwd/rev rounds); round B also inits BFS dist ----
  int nbN4 = CDIV(N,4);
  k_dde2<<<dim3(nbN4,2),256,0,stream>>>(offsT, degiI, ehr, offsH, deghI, etH,
      topic, topic, sB, sA, pe4, 0, 2, nullptr, nullptr, N);
  k_dde2<<<dim3(nbN4,2),256,0,stream>>>(offsT, degiI, ehr, offsH, deghI, etH,
      sB, sA, nullptr, nullptr, pe4, 1, 3, amask, dA, N);

  // ---- bounded BFS (3 rounds, ping-pong dA->dB->dA->dB) ----
  k_bfs_g<<<nbN4,256,0,stream>>>(offsT, degiI, ehr, offsH, deghI, etH, dA, dB, N);
  k_bfs_g<<<nbN4,256,0,stream>>>(offsT, degiI, ehr, offsH, deghI, etH, dB, dA, N);
  k_bfs_g<<<nbN4,256,0,stream>>>(offsT, degiI, ehr, offsH, deghI, etH, dA, dB, N);

  // ---- small dense (bias2 needed by relC epilogue) ----
  k_smalls<<<7,256,0,stream>>>(dist_e, W_enc, distW, nontext, encnt, q, W1, b1, bias2);

  // ---- relC = rel @ [WmB0 | WmB1 | W1r], bias2 folded into vrel cols ----
  k_bgemm<768,6,6,true,1><<<dim3(CDIV(R,32),6),256,0,stream>>>(rel, nullptr, nullptr, BIGK1, pbRelC, relC,
      bias2,nullptr,nullptr,nullptr,nullptr,nullptr,nullptr, R, 256);

  // ---- encoder (fused PE epilogue, bf16 h only; MR=2, CT=2) ----
  k_bgemm<256,2,3,true,2><<<dim3(CDIV(Ntext,64),2),256,0,stream>>>(ent, nullptr, nullptr, BIGK1, pbWenc, hB1,
      b_enc, W_enc, pe4, dB, topic, amask, distW, Ntext, 256);
  k_encnt_fill<<<N-Ntext,256,0,stream>>>(encnt, b_enc, W_enc, pe4, dB, topic, amask, distW, hB1, Ntext);

  // ---- 2-layer gated GNN (all-bf16 h; MR=2, CT=2 GEMMs) ----
  for (int l=0;l<2;l++){
    const u16* pT = l ? pbWmT1 : pbWmT0;
    const u16* pGU = l ? pbGU1 : pbGU0;
    u16* hinB  = l ? hB2 : hB1;
    u16* houtB = l ? hB1 : hB2;
    k_bgemm<256,2,1,false,2><<<dim3(CDIV(N,64),2),256,0,stream>>>(nullptr, hinB, nullptr, BIGK1, pT, hmB,
        nullptr,nullptr,nullptr,nullptr,nullptr,nullptr,nullptr, N, 256);
    k_agg<<<CDIV(N,4),256,0,stream>>>(offsT, degiI, ehr, hmB, relC, l*256, aggB, N);
    k_bgemm<512,2,4,false,2><<<dim3(CDIV(N,64),2),256,0,stream>>>(nullptr, hinB, aggB, 256, pGU, houtB,
        nullptr,nullptr,nullptr,nullptr,nullptr,nullptr,nullptr, N, 512);
  }

  // ---- UHT = h @ Wcomb, topic terms folded in epilogue (MR=2, CT=2) ----
  k_bgemm<512,2,5,false,2><<<dim3(CDIV(N,64),2),256,0,stream>>>(nullptr, hB1, nullptr, BIGK1, pbWcomb, UHT,
      tW,nullptr,nullptr,nullptr,topic,nullptr,nullptr, N, 256);

  // ---- final scorer (t-sorted CSR order) + anchor patch ----
  k_score<<<CDIV(N,4),256,0,stream>>>(offsT, degiI, ehr, eIdx, UHT, relC, W2, b2, out, N);
  k_patch<<<8,256,0,stream>>>(ai, as, h_ids, r_ids, t_ids, UHT, relC,
                              W1+(size_t)1024*256, W2, b2, out);
}